// Round 1
// baseline (5620.237 us; speedup 1.0000x reference)
//
#include <hip/hip_runtime.h>
#include <cmath>

#define H 128
#define GAMMA 0.1f
#define EPS 0.1f
#define NEG 0.01f
#define NGRAPH 256

// ---------------- precompute: W1t[k][j] = A[j,k] = W[j,k]-W[k,j]-gamma*(j==k)
//                  W2t[k][j] = lin_w[j,k]
__global__ void prep_kernel(const float* __restrict__ W, const float* __restrict__ lin_w,
                            float* __restrict__ W1t, float* __restrict__ W2t) {
    int idx = blockIdx.x * blockDim.x + threadIdx.x;   // 16384 threads
    int k = idx >> 7, j = idx & 127;
    float a = W[j * H + k] - W[k * H + j] - (j == k ? GAMMA : 0.f);
    W1t[k * H + j] = a;
    W2t[k * H + j] = lin_w[j * H + k];
}

// ---------------- edge aggregation: xagg[dst] += x[src]  (atomic f32)
__global__ void agg_kernel(const float* __restrict__ x, const int* __restrict__ src,
                           const int* __restrict__ dst, float* __restrict__ xagg, int E) {
    long long gid = (long long)blockIdx.x * blockDim.x + threadIdx.x;
    int e = (int)(gid >> 5);
    if (e >= E) return;
    int c = ((int)gid & 31) * 4;
    int s = src[e], d = dst[e];
    float4 v = *(const float4*)(x + (size_t)s * H + c);
    float* o = xagg + (size_t)d * H + c;
    atomicAdd(o + 0, v.x);
    atomicAdd(o + 1, v.y);
    atomicAdd(o + 2, v.z);
    atomicAdd(o + 3, v.w);
}

// ---------------- fused conv+update:
// xout = xin + EPS*tanh( xin @ A^T + xagg @ lin_w^T + bias )
// W1t/W2t are k-major (transposed) so weight reads are coalesced.
#define BR 32
#define LDW 132   // pad 128->132: tr groups land on distinct banks, float4-aligned
__global__ __launch_bounds__(256) void conv_kernel(
        const float* __restrict__ xin, const float* __restrict__ xagg,
        const float* __restrict__ W1t, const float* __restrict__ W2t,
        const float* __restrict__ bias, float* __restrict__ xout, int N) {
    __shared__ __align__(16) float sxin[BR][LDW];
    __shared__ __align__(16) float sxag[BR][LDW];
    int tile = blockIdx.x * BR;
    int tid = threadIdx.x;

    // stage x tiles (coalesced float4 along k)
    for (int i = tid; i < BR * (H / 4); i += 256) {
        int r = i >> 5, k4 = (i & 31) * 4;
        int row = tile + r;
        float4 vi = make_float4(0.f, 0.f, 0.f, 0.f);
        float4 va = make_float4(0.f, 0.f, 0.f, 0.f);
        if (row < N) {
            vi = *(const float4*)(xin + (size_t)row * H + k4);
            va = *(const float4*)(xagg + (size_t)row * H + k4);
        }
        *(float4*)&sxin[r][k4] = vi;
        *(float4*)&sxag[r][k4] = va;
    }
    __syncthreads();

    int tr = tid >> 5;          // 0..7 -> rows tr*4 .. tr*4+3
    int c0 = (tid & 31) * 4;    // cols c0 .. c0+3
    float acc[4][4] = {{0.f}};

    for (int k = 0; k < H; k += 4) {
        float4 xi[4], xa[4], w1[4], w2[4];
#pragma unroll
        for (int rr = 0; rr < 4; ++rr) {
            xi[rr] = *(const float4*)&sxin[tr * 4 + rr][k];
            xa[rr] = *(const float4*)&sxag[tr * 4 + rr][k];
        }
#pragma unroll
        for (int kk = 0; kk < 4; ++kk) {
            w1[kk] = *(const float4*)(W1t + (size_t)(k + kk) * H + c0);
            w2[kk] = *(const float4*)(W2t + (size_t)(k + kk) * H + c0);
        }
#pragma unroll
        for (int rr = 0; rr < 4; ++rr) {
            const float* xiv = (const float*)&xi[rr];
            const float* xav = (const float*)&xa[rr];
#pragma unroll
            for (int kk = 0; kk < 4; ++kk) {
                float xv = xiv[kk], av = xav[kk];
                acc[rr][0] += xv * ((const float*)&w1[kk])[0] + av * ((const float*)&w2[kk])[0];
                acc[rr][1] += xv * ((const float*)&w1[kk])[1] + av * ((const float*)&w2[kk])[1];
                acc[rr][2] += xv * ((const float*)&w1[kk])[2] + av * ((const float*)&w2[kk])[2];
                acc[rr][3] += xv * ((const float*)&w1[kk])[3] + av * ((const float*)&w2[kk])[3];
            }
        }
    }

    float4 bv = *(const float4*)(bias + c0);
#pragma unroll
    for (int rr = 0; rr < 4; ++rr) {
        int row = tile + tr * 4 + rr;
        if (row < N) {
            float4 xi = *(const float4*)&sxin[tr * 4 + rr][c0];
            float4 o;
            o.x = xi.x + EPS * tanhf(acc[rr][0] + bv.x);
            o.y = xi.y + EPS * tanhf(acc[rr][1] + bv.y);
            o.z = xi.z + EPS * tanhf(acc[rr][2] + bv.z);
            o.w = xi.w + EPS * tanhf(acc[rr][3] + bv.w);
            *(float4*)(xout + (size_t)row * H + c0) = o;
        }
    }
}

// ---------------- triple pooling per graph (batch sorted -> contiguous ranges)
__global__ void pool_kernel(const float* __restrict__ x, const int* __restrict__ batch,
                            float* __restrict__ pooled, int N) {
    int g = blockIdx.x, tid = threadIdx.x;   // 128 threads, tid = feature
    int lo = 0, hi = N;
    while (lo < hi) { int mid = (lo + hi) >> 1; if (batch[mid] < g) lo = mid + 1; else hi = mid; }
    int start = lo;
    hi = N;
    while (lo < hi) { int mid = (lo + hi) >> 1; if (batch[mid] < g + 1) lo = mid + 1; else hi = mid; }
    int end = lo;
    float sum = 0.f, mx = -INFINITY;
    for (int n = start; n < end; ++n) {
        float v = x[(size_t)n * H + tid];
        sum += v;
        mx = fmaxf(mx, v);
    }
    int cnt = end - start;
    pooled[g * 384 + tid] = sum;
    pooled[g * 384 + 128 + tid] = (cnt > 0) ? mx : 0.f;
    pooled[g * 384 + 256 + tid] = sum / (float)(cnt > 0 ? cnt : 1);
}

// ---------------- final 2-layer MLP with leaky relu
__global__ void mlp_kernel(const float* __restrict__ pooled, const float* __restrict__ l1_w,
                           const float* __restrict__ l1_b, const float* __restrict__ l2_w,
                           const float* __restrict__ l2_b, float* __restrict__ out) {
    __shared__ __align__(16) float sp[384];
    __shared__ __align__(16) float sh[192];
    int g = blockIdx.x, tid = threadIdx.x;  // 256 threads
    for (int i = tid; i < 384; i += 256) sp[i] = pooled[g * 384 + i];
    __syncthreads();
    if (tid < 192) {
        float acc = l1_b[tid];
        const float* wr = l1_w + (size_t)tid * 384;
        for (int k = 0; k < 384; k += 4) {
            float4 w = *(const float4*)(wr + k);
            float4 p = *(const float4*)(sp + k);
            acc += w.x * p.x + w.y * p.y + w.z * p.z + w.w * p.w;
        }
        sh[tid] = acc > 0.f ? acc : NEG * acc;
    }
    __syncthreads();
    if (tid < 64) {
        float acc = l2_b[tid];
        const float* wr = l2_w + (size_t)tid * 192;
        for (int k = 0; k < 192; k += 4) {
            float4 w = *(const float4*)(wr + k);
            float4 p = *(const float4*)(sh + k);
            acc += w.x * p.x + w.y * p.y + w.z * p.z + w.w * p.w;
        }
        out[g * 64 + tid] = acc > 0.f ? acc : NEG * acc;
    }
}

extern "C" void kernel_launch(void* const* d_in, const int* in_sizes, int n_in,
                              void* d_out, int out_size, void* d_ws, size_t ws_size,
                              hipStream_t stream) {
    const float* x0    = (const float*)d_in[0];
    const int*   edge  = (const int*)d_in[1];
    const int*   batch = (const int*)d_in[2];
    const float* W     = (const float*)d_in[3];
    const float* bias  = (const float*)d_in[4];
    const float* lin_w = (const float*)d_in[5];
    const float* l1_w  = (const float*)d_in[6];
    const float* l1_b  = (const float*)d_in[7];
    const float* l2_w  = (const float*)d_in[8];
    const float* l2_b  = (const float*)d_in[9];
    float* out = (float*)d_out;

    int N = in_sizes[0] / H;
    int E = in_sizes[1] / 2;
    const int* src = edge;
    const int* dst = edge + E;

    float* ws = (float*)d_ws;
    size_t nh = (size_t)N * H;
    float* xA     = ws;
    float* xB     = xA + nh;
    float* xagg   = xB + nh;
    float* W1t    = xagg + nh;
    float* W2t    = W1t + H * H;
    float* pooled = W2t + H * H;

    prep_kernel<<<(H * H) / 256, 256, 0, stream>>>(W, lin_w, W1t, W2t);

    const float* xcur = x0;
    for (int it = 0; it < 5; ++it) {
        hipMemsetAsync(xagg, 0, nh * sizeof(float), stream);
        long long tot = (long long)E * 32;
        agg_kernel<<<(int)((tot + 255) / 256), 256, 0, stream>>>(xcur, src, dst, xagg, E);
        float* xnext = (it & 1) ? xB : xA;
        conv_kernel<<<(N + BR - 1) / BR, 256, 0, stream>>>(xcur, xagg, W1t, W2t, bias, xnext, N);
        xcur = xnext;
    }

    pool_kernel<<<NGRAPH, H, 0, stream>>>(xcur, batch, pooled, N);
    mlp_kernel<<<NGRAPH, 256, 0, stream>>>(pooled, l1_w, l1_b, l2_w, l2_b, out);
}

// Round 2
// 925.003 us; speedup vs baseline: 6.0759x; 6.0759x over previous
//
#include <hip/hip_runtime.h>
#include <cmath>

#define H 128
#define GAMMA 0.1f
#define EPS 0.1f
#define NEG 0.01f
#define NGRAPH 256

// ---------------- precompute: W1t[k][j] = A[j,k] = W[j,k]-W[k,j]-gamma*(j==k)
//                  W2t[k][j] = lin_w[j,k]
__global__ void prep_kernel(const float* __restrict__ W, const float* __restrict__ lin_w,
                            float* __restrict__ W1t, float* __restrict__ W2t) {
    int idx = blockIdx.x * blockDim.x + threadIdx.x;   // 16384 threads
    int k = idx >> 7, j = idx & 127;
    float a = W[j * H + k] - W[k * H + j] - (j == k ? GAMMA : 0.f);
    W1t[k * H + j] = a;
    W2t[k * H + j] = lin_w[j * H + k];
}

// ---------------- CSR build: count in-degree per dst
__global__ void count_kernel(const int* __restrict__ dst, int* __restrict__ deg, int E) {
    int e = blockIdx.x * blockDim.x + threadIdx.x;
    if (e < E) atomicAdd(&deg[dst[e]], 1);
}

// single-block exclusive scan over deg[N] -> row_start[N+1], cursor copy
__global__ __launch_bounds__(1024) void scan_kernel(const int* __restrict__ deg,
                                                    int* __restrict__ row_start,
                                                    int* __restrict__ cursor, int N) {
    __shared__ int sums[1024];
    int tid = threadIdx.x;
    int chunk = (N + 1023) / 1024;
    int lo = tid * chunk, hi = min(lo + chunk, N);
    int s = 0;
    for (int i = lo; i < hi; ++i) s += deg[i];
    sums[tid] = s;
    __syncthreads();
    for (int off = 1; off < 1024; off <<= 1) {
        int v = (tid >= off) ? sums[tid - off] : 0;
        __syncthreads();
        sums[tid] += v;
        __syncthreads();
    }
    int base = (tid == 0) ? 0 : sums[tid - 1];   // exclusive prefix of my chunk
    for (int i = lo; i < hi; ++i) {
        row_start[i] = base;
        cursor[i] = base;
        base += deg[i];
    }
    if (tid == 1023) row_start[N] = base;        // == E
}

// bucket-fill: csr_src grouped by dst
__global__ void fill_kernel(const int* __restrict__ src, const int* __restrict__ dst,
                            int* __restrict__ cursor, int* __restrict__ csr_src, int E) {
    int e = blockIdx.x * blockDim.x + threadIdx.x;
    if (e < E) {
        int p = atomicAdd(&cursor[dst[e]], 1);
        csr_src[p] = src[e];
    }
}

// ---------------- gather aggregation: one wave per dst node, no atomics.
// lane l holds features [2l, 2l+1]; edge indices broadcast via shfl.
__global__ __launch_bounds__(256) void gather_agg(const float* __restrict__ x,
        const int* __restrict__ row_start, const int* __restrict__ csr_src,
        float* __restrict__ xagg, int N) {
    int node = blockIdx.x * 4 + (threadIdx.x >> 6);
    if (node >= N) return;
    int lane = threadIdx.x & 63;
    int begin = row_start[node], end = row_start[node + 1];
    float2 acc0 = make_float2(0.f, 0.f), acc1 = make_float2(0.f, 0.f);
    for (int base = begin; base < end; base += 64) {
        int cnt = min(64, end - base);
        int myidx = (lane < cnt) ? csr_src[base + lane] : 0;
        int j = 0;
        for (; j + 1 < cnt; j += 2) {
            int s0 = __shfl(myidx, j);
            int s1 = __shfl(myidx, j + 1);
            float2 v0 = *(const float2*)(x + (size_t)s0 * H + lane * 2);
            float2 v1 = *(const float2*)(x + (size_t)s1 * H + lane * 2);
            acc0.x += v0.x; acc0.y += v0.y;
            acc1.x += v1.x; acc1.y += v1.y;
        }
        if (j < cnt) {
            int s0 = __shfl(myidx, j);
            float2 v0 = *(const float2*)(x + (size_t)s0 * H + lane * 2);
            acc0.x += v0.x; acc0.y += v0.y;
        }
    }
    float2 o = make_float2(acc0.x + acc1.x, acc0.y + acc1.y);
    *(float2*)(xagg + (size_t)node * H + lane * 2) = o;
}

// ---------------- fused conv+update:
// xout = xin + EPS*tanh( xin @ A^T + xagg @ lin_w^T + bias )
#define BR 32
#define LDW 132
__global__ __launch_bounds__(256) void conv_kernel(
        const float* __restrict__ xin, const float* __restrict__ xagg,
        const float* __restrict__ W1t, const float* __restrict__ W2t,
        const float* __restrict__ bias, float* __restrict__ xout, int N) {
    __shared__ __align__(16) float sxin[BR][LDW];
    __shared__ __align__(16) float sxag[BR][LDW];
    int tile = blockIdx.x * BR;
    int tid = threadIdx.x;

    for (int i = tid; i < BR * (H / 4); i += 256) {
        int r = i >> 5, k4 = (i & 31) * 4;
        int row = tile + r;
        float4 vi = make_float4(0.f, 0.f, 0.f, 0.f);
        float4 va = make_float4(0.f, 0.f, 0.f, 0.f);
        if (row < N) {
            vi = *(const float4*)(xin + (size_t)row * H + k4);
            va = *(const float4*)(xagg + (size_t)row * H + k4);
        }
        *(float4*)&sxin[r][k4] = vi;
        *(float4*)&sxag[r][k4] = va;
    }
    __syncthreads();

    int tr = tid >> 5;
    int c0 = (tid & 31) * 4;
    float acc[4][4] = {{0.f}};

    for (int k = 0; k < H; k += 4) {
        float4 xi[4], xa[4], w1[4], w2[4];
#pragma unroll
        for (int rr = 0; rr < 4; ++rr) {
            xi[rr] = *(const float4*)&sxin[tr * 4 + rr][k];
            xa[rr] = *(const float4*)&sxag[tr * 4 + rr][k];
        }
#pragma unroll
        for (int kk = 0; kk < 4; ++kk) {
            w1[kk] = *(const float4*)(W1t + (size_t)(k + kk) * H + c0);
            w2[kk] = *(const float4*)(W2t + (size_t)(k + kk) * H + c0);
        }
#pragma unroll
        for (int rr = 0; rr < 4; ++rr) {
            const float* xiv = (const float*)&xi[rr];
            const float* xav = (const float*)&xa[rr];
#pragma unroll
            for (int kk = 0; kk < 4; ++kk) {
                float xv = xiv[kk], av = xav[kk];
                acc[rr][0] += xv * ((const float*)&w1[kk])[0] + av * ((const float*)&w2[kk])[0];
                acc[rr][1] += xv * ((const float*)&w1[kk])[1] + av * ((const float*)&w2[kk])[1];
                acc[rr][2] += xv * ((const float*)&w1[kk])[2] + av * ((const float*)&w2[kk])[2];
                acc[rr][3] += xv * ((const float*)&w1[kk])[3] + av * ((const float*)&w2[kk])[3];
            }
        }
    }

    float4 bv = *(const float4*)(bias + c0);
#pragma unroll
    for (int rr = 0; rr < 4; ++rr) {
        int row = tile + tr * 4 + rr;
        if (row < N) {
            float4 xi = *(const float4*)&sxin[tr * 4 + rr][c0];
            float4 o;
            o.x = xi.x + EPS * tanhf(acc[rr][0] + bv.x);
            o.y = xi.y + EPS * tanhf(acc[rr][1] + bv.y);
            o.z = xi.z + EPS * tanhf(acc[rr][2] + bv.z);
            o.w = xi.w + EPS * tanhf(acc[rr][3] + bv.w);
            *(float4*)(xout + (size_t)row * H + c0) = o;
        }
    }
}

// ---------------- triple pooling per graph (batch sorted -> contiguous ranges)
__global__ void pool_kernel(const float* __restrict__ x, const int* __restrict__ batch,
                            float* __restrict__ pooled, int N) {
    int g = blockIdx.x, tid = threadIdx.x;   // 128 threads, tid = feature
    int lo = 0, hi = N;
    while (lo < hi) { int mid = (lo + hi) >> 1; if (batch[mid] < g) lo = mid + 1; else hi = mid; }
    int start = lo;
    hi = N;
    while (lo < hi) { int mid = (lo + hi) >> 1; if (batch[mid] < g + 1) lo = mid + 1; else hi = mid; }
    int end = lo;
    float sum = 0.f, mx = -INFINITY;
    for (int n = start; n < end; ++n) {
        float v = x[(size_t)n * H + tid];
        sum += v;
        mx = fmaxf(mx, v);
    }
    int cnt = end - start;
    pooled[g * 384 + tid] = sum;
    pooled[g * 384 + 128 + tid] = (cnt > 0) ? mx : 0.f;
    pooled[g * 384 + 256 + tid] = sum / (float)(cnt > 0 ? cnt : 1);
}

// ---------------- final 2-layer MLP with leaky relu
__global__ void mlp_kernel(const float* __restrict__ pooled, const float* __restrict__ l1_w,
                           const float* __restrict__ l1_b, const float* __restrict__ l2_w,
                           const float* __restrict__ l2_b, float* __restrict__ out) {
    __shared__ __align__(16) float sp[384];
    __shared__ __align__(16) float sh[192];
    int g = blockIdx.x, tid = threadIdx.x;  // 256 threads
    for (int i = tid; i < 384; i += 256) sp[i] = pooled[g * 384 + i];
    __syncthreads();
    if (tid < 192) {
        float acc = l1_b[tid];
        const float* wr = l1_w + (size_t)tid * 384;
        for (int k = 0; k < 384; k += 4) {
            float4 w = *(const float4*)(wr + k);
            float4 p = *(const float4*)(sp + k);
            acc += w.x * p.x + w.y * p.y + w.z * p.z + w.w * p.w;
        }
        sh[tid] = acc > 0.f ? acc : NEG * acc;
    }
    __syncthreads();
    if (tid < 64) {
        float acc = l2_b[tid];
        const float* wr = l2_w + (size_t)tid * 192;
        for (int k = 0; k < 192; k += 4) {
            float4 w = *(const float4*)(wr + k);
            float4 p = *(const float4*)(sh + k);
            acc += w.x * p.x + w.y * p.y + w.z * p.z + w.w * p.w;
        }
        out[g * 64 + tid] = acc > 0.f ? acc : NEG * acc;
    }
}

extern "C" void kernel_launch(void* const* d_in, const int* in_sizes, int n_in,
                              void* d_out, int out_size, void* d_ws, size_t ws_size,
                              hipStream_t stream) {
    const float* x0    = (const float*)d_in[0];
    const int*   edge  = (const int*)d_in[1];
    const int*   batch = (const int*)d_in[2];
    const float* W     = (const float*)d_in[3];
    const float* bias  = (const float*)d_in[4];
    const float* lin_w = (const float*)d_in[5];
    const float* l1_w  = (const float*)d_in[6];
    const float* l1_b  = (const float*)d_in[7];
    const float* l2_w  = (const float*)d_in[8];
    const float* l2_b  = (const float*)d_in[9];
    float* out = (float*)d_out;

    int N = in_sizes[0] / H;
    int E = in_sizes[1] / 2;
    const int* src = edge;
    const int* dst = edge + E;

    float* ws = (float*)d_ws;
    size_t nh = (size_t)N * H;
    float* xA     = ws;
    float* xB     = xA + nh;
    float* xagg   = xB + nh;
    float* W1t    = xagg + nh;
    float* W2t    = W1t + H * H;
    float* pooled = W2t + H * H;
    int* deg       = (int*)(pooled + NGRAPH * 384);
    int* row_start = deg + N;          // N+1
    int* cursor    = row_start + N + 1;
    int* csr_src   = cursor + N;       // E

    prep_kernel<<<(H * H) / 256, 256, 0, stream>>>(W, lin_w, W1t, W2t);

    // ---- CSR build (once) ----
    hipMemsetAsync(deg, 0, (size_t)N * sizeof(int), stream);
    count_kernel<<<(E + 255) / 256, 256, 0, stream>>>(dst, deg, E);
    scan_kernel<<<1, 1024, 0, stream>>>(deg, row_start, cursor, N);
    fill_kernel<<<(E + 255) / 256, 256, 0, stream>>>(src, dst, cursor, csr_src, E);

    const float* xcur = x0;
    for (int it = 0; it < 5; ++it) {
        gather_agg<<<(N + 3) / 4, 256, 0, stream>>>(xcur, row_start, csr_src, xagg, N);
        float* xnext = (it & 1) ? xB : xA;
        conv_kernel<<<(N + BR - 1) / BR, 256, 0, stream>>>(xcur, xagg, W1t, W2t, bias, xnext, N);
        xcur = xnext;
    }

    pool_kernel<<<NGRAPH, H, 0, stream>>>(xcur, batch, pooled, N);
    mlp_kernel<<<NGRAPH, 256, 0, stream>>>(pooled, l1_w, l1_b, l2_w, l2_b, out);
}

// Round 3
// 479.871 us; speedup vs baseline: 11.7120x; 1.9276x over previous
//
#include <hip/hip_runtime.h>
#include <hip/hip_fp16.h>
#include <cmath>

#define H 128
#define GAMMA 0.1f
#define EPS 0.1f
#define NEG 0.01f
#define NGRAPH 256

typedef _Float16 half_t;
typedef _Float16 f16x8 __attribute__((ext_vector_type(8)));
typedef _Float16 f16x2 __attribute__((ext_vector_type(2)));
typedef float f32x4 __attribute__((ext_vector_type(4)));

__device__ __forceinline__ float fast_tanh(float v) {
    // tanh(v) = 1 - 2/(e^{2v}+1);  e^{2v} = 2^{v * 2/ln2}
    float e = __builtin_amdgcn_exp2f(v * 2.8853900817779268f);
    float r = __builtin_amdgcn_rcpf(e + 1.0f);
    return 1.0f - 2.0f * r;
}

// ---------------- precompute combined transposed weights, f16:
// WtT[j][k] (128 x 256): k<128 -> A[j][k] = W[j][k]-W[k][j]-gamma*delta ; k>=128 -> lin_w[j][k-128]
__global__ void prep_kernel(const float* __restrict__ W, const float* __restrict__ lin_w,
                            half_t* __restrict__ WtT) {
    int idx = blockIdx.x * 256 + threadIdx.x;   // 32768 threads
    int j = idx >> 8, k = idx & 255;
    float v;
    if (k < H) v = W[j * H + k] - W[k * H + j] - (j == k ? GAMMA : 0.f);
    else       v = lin_w[j * H + (k - H)];
    WtT[j * 256 + k] = (half_t)v;
}

// ---------------- f32 -> f16 cast (x0 -> xh)
__global__ void cast_kernel(const float* __restrict__ x, half_t* __restrict__ xh, int n4) {
    int i = blockIdx.x * 256 + threadIdx.x;
    if (i < n4) {
        float4 v = *(const float4*)(x + (size_t)i * 4);
        half_t h0 = (half_t)v.x, h1 = (half_t)v.y, h2 = (half_t)v.z, h3 = (half_t)v.w;
        half_t* o = xh + (size_t)i * 4;
        o[0] = h0; o[1] = h1; o[2] = h2; o[3] = h3;
    }
}

// ---------------- CSR build: count in-degree per dst
__global__ void count_kernel(const int* __restrict__ dst, int* __restrict__ deg, int E) {
    int e = blockIdx.x * blockDim.x + threadIdx.x;
    if (e < E) atomicAdd(&deg[dst[e]], 1);
}

// ---------------- hierarchical scan: deg[N] -> row_start[N+1], cursor
#define SCHUNK 2048
__global__ __launch_bounds__(256) void scan_part(const int* __restrict__ deg,
                                                 int* __restrict__ partials, int N) {
    __shared__ int red[256];
    int t = threadIdx.x, b = blockIdx.x;
    int base = b * SCHUNK + t * 8;
    int s = 0;
#pragma unroll
    for (int i = 0; i < 8; ++i) { int idx = base + i; if (idx < N) s += deg[idx]; }
    red[t] = s;
    __syncthreads();
    for (int off = 128; off > 0; off >>= 1) {
        if (t < off) red[t] += red[t + off];
        __syncthreads();
    }
    if (t == 0) partials[b] = red[0];
}

__global__ void scan_mid(const int* __restrict__ partials, int* __restrict__ blkoff, int nblk) {
    int lane = threadIdx.x;   // 64 threads
    int p = (lane < nblk) ? partials[lane] : 0;
    int v = p;
    for (int off = 1; off < 64; off <<= 1) {
        int u = __shfl_up(v, off);
        if (lane >= off) v += u;
    }
    if (lane < nblk) blkoff[lane] = v - p;
}

__global__ __launch_bounds__(256) void scan_final(const int* __restrict__ deg,
        const int* __restrict__ blkoff, int* __restrict__ row_start,
        int* __restrict__ cursor, int N, int E) {
    __shared__ int red[256];
    int t = threadIdx.x, b = blockIdx.x;
    int base = b * SCHUNK + t * 8;
    int v[8]; int s = 0;
#pragma unroll
    for (int i = 0; i < 8; ++i) { int idx = base + i; v[i] = (idx < N) ? deg[idx] : 0; s += v[i]; }
    red[t] = s;
    __syncthreads();
    for (int off = 1; off < 256; off <<= 1) {
        int u = (t >= off) ? red[t - off] : 0;
        __syncthreads();
        red[t] += u;
        __syncthreads();
    }
    int run = blkoff[b] + red[t] - s;   // exclusive prefix for this thread
#pragma unroll
    for (int i = 0; i < 8; ++i) {
        int idx = base + i;
        if (idx < N) { row_start[idx] = run; cursor[idx] = run; run += v[i]; }
    }
    if (b == 0 && t == 0) row_start[N] = E;
}

// bucket-fill: csr_src grouped by dst
__global__ void fill_kernel(const int* __restrict__ src, const int* __restrict__ dst,
                            int* __restrict__ cursor, int* __restrict__ csr_src, int E) {
    int e = blockIdx.x * blockDim.x + threadIdx.x;
    if (e < E) {
        int p = atomicAdd(&cursor[dst[e]], 1);
        csr_src[p] = src[e];
    }
}

// ---------------- gather aggregation (f16 in, f16 out, f32 accum): one wave per dst
__global__ __launch_bounds__(256) void gather_agg(const half_t* __restrict__ xh,
        const int* __restrict__ row_start, const int* __restrict__ csr_src,
        half_t* __restrict__ xaggh, int N) {
    int node = blockIdx.x * 4 + (threadIdx.x >> 6);
    if (node >= N) return;
    int lane = threadIdx.x & 63;
    int begin = row_start[node], end = row_start[node + 1];
    float a0 = 0.f, a1 = 0.f, b0 = 0.f, b1 = 0.f;
    for (int base = begin; base < end; base += 64) {
        int cnt = min(64, end - base);
        int myidx = (lane < cnt) ? csr_src[base + lane] : 0;
        int j = 0;
        for (; j + 1 < cnt; j += 2) {
            int s0 = __shfl(myidx, j);
            int s1 = __shfl(myidx, j + 1);
            f16x2 v0 = *(const f16x2*)(xh + (size_t)s0 * H + lane * 2);
            f16x2 v1 = *(const f16x2*)(xh + (size_t)s1 * H + lane * 2);
            a0 += (float)v0[0]; a1 += (float)v0[1];
            b0 += (float)v1[0]; b1 += (float)v1[1];
        }
        if (j < cnt) {
            int s0 = __shfl(myidx, j);
            f16x2 v0 = *(const f16x2*)(xh + (size_t)s0 * H + lane * 2);
            a0 += (float)v0[0]; a1 += (float)v0[1];
        }
    }
    f16x2 o; o[0] = (half_t)(a0 + b0); o[1] = (half_t)(a1 + b1);
    *(f16x2*)(xaggh + (size_t)node * H + lane * 2) = o;
}

// ---------------- fused conv+update via f16 MFMA:
// xout = xin + EPS*tanh( [xh | xaggh] @ WtT^T + bias ), also emits f16 copy.
// Block: 256 thr = 4 waves; 128 rows/block; wave handles 32 rows x 128 cols.
#define CROWS 128
#define BLDW 264   // 256 + 8 halfs pad -> 2-way (free) LDS bank aliasing
__global__ __launch_bounds__(256) void conv_mfma(
        const float* __restrict__ xin, const half_t* __restrict__ xh,
        const half_t* __restrict__ xaggh, const half_t* __restrict__ WtT,
        const float* __restrict__ bias,
        float* __restrict__ xout, half_t* __restrict__ xouth, int N) {
    __shared__ __align__(16) half_t sB[128 * BLDW];
    int tid = threadIdx.x;
    // stage weights 128x256 -> LDS (padded rows)
    for (int c = tid; c < 4096; c += 256) {
        int j = c >> 5, off = (c & 31) * 8;
        *(f16x8*)&sB[j * BLDW + off] = *(const f16x8*)(WtT + j * 256 + off);
    }
    __syncthreads();

    int wave = tid >> 6, lane = tid & 63;
    int q = lane >> 4, m = lane & 15;
    int rowbase = blockIdx.x * CROWS + wave * 32;

    f32x4 acc[2][8];
#pragma unroll
    for (int rt = 0; rt < 2; ++rt)
#pragma unroll
        for (int ct = 0; ct < 8; ++ct) acc[rt][ct] = (f32x4){0.f, 0.f, 0.f, 0.f};

#pragma unroll
    for (int s = 0; s < 8; ++s) {
        const half_t* srcA = (s < 4) ? xh : xaggh;
        int koff = (s & 3) * 32 + q * 8;
        f16x8 afrag[2];
#pragma unroll
        for (int rt = 0; rt < 2; ++rt) {
            int row = rowbase + rt * 16 + m;
            row = min(row, N - 1);
            afrag[rt] = *(const f16x8*)(srcA + (size_t)row * H + koff);
        }
#pragma unroll
        for (int ct = 0; ct < 8; ++ct) {
            f16x8 bfrag = *(const f16x8*)&sB[(ct * 16 + m) * BLDW + s * 32 + q * 8];
            acc[0][ct] = __builtin_amdgcn_mfma_f32_16x16x32_f16(afrag[0], bfrag, acc[0][ct], 0, 0, 0);
            acc[1][ct] = __builtin_amdgcn_mfma_f32_16x16x32_f16(afrag[1], bfrag, acc[1][ct], 0, 0, 0);
        }
    }

#pragma unroll
    for (int rt = 0; rt < 2; ++rt) {
#pragma unroll
        for (int r = 0; r < 4; ++r) {
            int row = rowbase + rt * 16 + q * 4 + r;
            if (row < N) {
#pragma unroll
                for (int ct = 0; ct < 8; ++ct) {
                    int col = ct * 16 + m;
                    float c = acc[rt][ct][r] + bias[col];
                    float o = xin[(size_t)row * H + col] + EPS * fast_tanh(c);
                    xout[(size_t)row * H + col] = o;
                    xouth[(size_t)row * H + col] = (half_t)o;
                }
            }
        }
    }
}

// ---------------- triple pooling per graph (batch sorted -> contiguous ranges)
__global__ void pool_kernel(const float* __restrict__ x, const int* __restrict__ batch,
                            float* __restrict__ pooled, int N) {
    int g = blockIdx.x, tid = threadIdx.x;   // 128 threads, tid = feature
    int lo = 0, hi = N;
    while (lo < hi) { int mid = (lo + hi) >> 1; if (batch[mid] < g) lo = mid + 1; else hi = mid; }
    int start = lo;
    hi = N;
    while (lo < hi) { int mid = (lo + hi) >> 1; if (batch[mid] < g + 1) lo = mid + 1; else hi = mid; }
    int end = lo;
    float sum = 0.f, mx = -INFINITY;
    for (int n = start; n < end; ++n) {
        float v = x[(size_t)n * H + tid];
        sum += v;
        mx = fmaxf(mx, v);
    }
    int cnt = end - start;
    pooled[g * 384 + tid] = sum;
    pooled[g * 384 + 128 + tid] = (cnt > 0) ? mx : 0.f;
    pooled[g * 384 + 256 + tid] = sum / (float)(cnt > 0 ? cnt : 1);
}

// ---------------- final 2-layer MLP with leaky relu
__global__ void mlp_kernel(const float* __restrict__ pooled, const float* __restrict__ l1_w,
                           const float* __restrict__ l1_b, const float* __restrict__ l2_w,
                           const float* __restrict__ l2_b, float* __restrict__ out) {
    __shared__ __align__(16) float sp[384];
    __shared__ __align__(16) float sh[192];
    int g = blockIdx.x, tid = threadIdx.x;  // 256 threads
    for (int i = tid; i < 384; i += 256) sp[i] = pooled[g * 384 + i];
    __syncthreads();
    if (tid < 192) {
        float acc = l1_b[tid];
        const float* wr = l1_w + (size_t)tid * 384;
        for (int k = 0; k < 384; k += 4) {
            float4 w = *(const float4*)(wr + k);
            float4 p = *(const float4*)(sp + k);
            acc += w.x * p.x + w.y * p.y + w.z * p.z + w.w * p.w;
        }
        sh[tid] = acc > 0.f ? acc : NEG * acc;
    }
    __syncthreads();
    if (tid < 64) {
        float acc = l2_b[tid];
        const float* wr = l2_w + (size_t)tid * 192;
        for (int k = 0; k < 192; k += 4) {
            float4 w = *(const float4*)(wr + k);
            float4 p = *(const float4*)(sh + k);
            acc += w.x * p.x + w.y * p.y + w.z * p.z + w.w * p.w;
        }
        out[g * 64 + tid] = acc > 0.f ? acc : NEG * acc;
    }
}

extern "C" void kernel_launch(void* const* d_in, const int* in_sizes, int n_in,
                              void* d_out, int out_size, void* d_ws, size_t ws_size,
                              hipStream_t stream) {
    const float* x0    = (const float*)d_in[0];
    const int*   edge  = (const int*)d_in[1];
    const int*   batch = (const int*)d_in[2];
    const float* W     = (const float*)d_in[3];
    const float* bias  = (const float*)d_in[4];
    const float* lin_w = (const float*)d_in[5];
    const float* l1_w  = (const float*)d_in[6];
    const float* l1_b  = (const float*)d_in[7];
    const float* l2_w  = (const float*)d_in[8];
    const float* l2_b  = (const float*)d_in[9];
    float* out = (float*)d_out;

    int N = in_sizes[0] / H;
    int E = in_sizes[1] / 2;
    const int* src = edge;
    const int* dst = edge + E;

    size_t nh = (size_t)N * H;
    float* xA      = (float*)d_ws;
    float* xB      = xA + nh;
    float* pooled  = xB + nh;
    half_t* xhA    = (half_t*)(pooled + NGRAPH * 384);
    half_t* xhB    = xhA + nh;
    half_t* xaggh  = xhB + nh;
    half_t* WtT    = xaggh + nh;              // 128*256
    int* deg       = (int*)(WtT + 128 * 256);
    int* row_start = deg + N;                 // N+1
    int* cursor    = row_start + N + 1;
    int* csr_src   = cursor + N;              // E
    int* partials  = csr_src + E;             // 64
    int* blkoff    = partials + 64;           // 64

    prep_kernel<<<128, 256, 0, stream>>>(W, lin_w, WtT);
    cast_kernel<<<((int)(nh / 4) + 255) / 256, 256, 0, stream>>>(x0, xhA, (int)(nh / 4));

    // ---- CSR build (once) ----
    hipMemsetAsync(deg, 0, (size_t)N * sizeof(int), stream);
    count_kernel<<<(E + 255) / 256, 256, 0, stream>>>(dst, deg, E);
    int nblk = (N + SCHUNK - 1) / SCHUNK;
    scan_part<<<nblk, 256, 0, stream>>>(deg, partials, N);
    scan_mid<<<1, 64, 0, stream>>>(partials, blkoff, nblk);
    scan_final<<<nblk, 256, 0, stream>>>(deg, blkoff, row_start, cursor, N, E);
    fill_kernel<<<(E + 255) / 256, 256, 0, stream>>>(src, dst, cursor, csr_src, E);

    const float* xcur = x0;
    const half_t* xcur_h = xhA;
    for (int it = 0; it < 5; ++it) {
        gather_agg<<<(N + 3) / 4, 256, 0, stream>>>(xcur_h, row_start, csr_src, xaggh, N);
        float* xnext = (it & 1) ? xB : xA;
        half_t* xnext_h = (it & 1) ? xhA : xhB;
        conv_mfma<<<(N + CROWS - 1) / CROWS, 256, 0, stream>>>(
            xcur, xcur_h, xaggh, WtT, bias, xnext, xnext_h, N);
        xcur = xnext;
        xcur_h = xnext_h;
    }

    pool_kernel<<<NGRAPH, H, 0, stream>>>(xcur, batch, pooled, N);
    mlp_kernel<<<NGRAPH, 256, 0, stream>>>(pooled, l1_w, l1_b, l2_w, l2_b, out);
}

// Round 4
// 411.860 us; speedup vs baseline: 13.6460x; 1.1651x over previous
//
#include <hip/hip_runtime.h>
#include <hip/hip_fp16.h>
#include <cmath>

#define H 128
#define GAMMA 0.1f
#define EPS 0.1f
#define NEG 0.01f
#define NGRAPH 256

typedef _Float16 half_t;
typedef _Float16 f16x8 __attribute__((ext_vector_type(8)));
typedef _Float16 f16x4 __attribute__((ext_vector_type(4)));
typedef _Float16 f16x2 __attribute__((ext_vector_type(2)));
typedef float f32x4 __attribute__((ext_vector_type(4)));

__device__ __forceinline__ float fast_tanh(float v) {
    float e = __builtin_amdgcn_exp2f(v * 2.8853900817779268f);
    float r = __builtin_amdgcn_rcpf(e + 1.0f);
    return 1.0f - 2.0f * r;
}

// ---------------- precompute combined transposed weights, f16
__global__ void prep_kernel(const float* __restrict__ W, const float* __restrict__ lin_w,
                            half_t* __restrict__ WtT) {
    int idx = blockIdx.x * 256 + threadIdx.x;   // 32768 threads
    int j = idx >> 8, k = idx & 255;
    float v;
    if (k < H) v = W[j * H + k] - W[k * H + j] - (j == k ? GAMMA : 0.f);
    else       v = lin_w[j * H + (k - H)];
    WtT[j * 256 + k] = (half_t)v;
}

// ---------------- f32 -> f16 cast (x0 -> xh)
__global__ void cast_kernel(const float* __restrict__ x, half_t* __restrict__ xh, int n4) {
    int i = blockIdx.x * 256 + threadIdx.x;
    if (i < n4) {
        float4 v = *(const float4*)(x + (size_t)i * 4);
        half_t* o = xh + (size_t)i * 4;
        o[0] = (half_t)v.x; o[1] = (half_t)v.y; o[2] = (half_t)v.z; o[3] = (half_t)v.w;
    }
}

// ---------------- CSR build
__global__ void count_kernel(const int* __restrict__ dst, int* __restrict__ deg, int E) {
    int e = blockIdx.x * blockDim.x + threadIdx.x;
    if (e < E) atomicAdd(&deg[dst[e]], 1);
}

#define SCHUNK 2048
__global__ __launch_bounds__(256) void scan_part(const int* __restrict__ deg,
                                                 int* __restrict__ partials, int N) {
    __shared__ int red[256];
    int t = threadIdx.x, b = blockIdx.x;
    int base = b * SCHUNK + t * 8;
    int s = 0;
#pragma unroll
    for (int i = 0; i < 8; ++i) { int idx = base + i; if (idx < N) s += deg[idx]; }
    red[t] = s;
    __syncthreads();
    for (int off = 128; off > 0; off >>= 1) {
        if (t < off) red[t] += red[t + off];
        __syncthreads();
    }
    if (t == 0) partials[b] = red[0];
}

__global__ void scan_mid(const int* __restrict__ partials, int* __restrict__ blkoff, int nblk) {
    int lane = threadIdx.x;   // 64 threads
    int p = (lane < nblk) ? partials[lane] : 0;
    int v = p;
    for (int off = 1; off < 64; off <<= 1) {
        int u = __shfl_up(v, off);
        if (lane >= off) v += u;
    }
    if (lane < nblk) blkoff[lane] = v - p;
}

__global__ __launch_bounds__(256) void scan_final(const int* __restrict__ deg,
        const int* __restrict__ blkoff, int* __restrict__ row_start,
        int* __restrict__ cursor, int N, int E) {
    __shared__ int red[256];
    int t = threadIdx.x, b = blockIdx.x;
    int base = b * SCHUNK + t * 8;
    int v[8]; int s = 0;
#pragma unroll
    for (int i = 0; i < 8; ++i) { int idx = base + i; v[i] = (idx < N) ? deg[idx] : 0; s += v[i]; }
    red[t] = s;
    __syncthreads();
    for (int off = 1; off < 256; off <<= 1) {
        int u = (t >= off) ? red[t - off] : 0;
        __syncthreads();
        red[t] += u;
        __syncthreads();
    }
    int run = blkoff[b] + red[t] - s;
#pragma unroll
    for (int i = 0; i < 8; ++i) {
        int idx = base + i;
        if (idx < N) { row_start[idx] = run; cursor[idx] = run; run += v[i]; }
    }
    if (b == 0 && t == 0) row_start[N] = E;
}

__global__ void fill_kernel(const int* __restrict__ src, const int* __restrict__ dst,
                            int* __restrict__ cursor, int* __restrict__ csr_src, int E) {
    int e = blockIdx.x * blockDim.x + threadIdx.x;
    if (e < E) {
        int p = atomicAdd(&cursor[dst[e]], 1);
        csr_src[p] = src[e];
    }
}

// ---------------- gather aggregation: one wave per dst, 2 rows per load step.
// lane = 32*half + li ; lane covers features [4*li, 4*li+4) (f16x4 = 8B).
// half 0 takes even edges, half 1 odd edges; combined via shfl_xor(32).
__global__ __launch_bounds__(256) void gather_agg(const half_t* __restrict__ xh,
        const int* __restrict__ row_start, const int* __restrict__ csr_src,
        half_t* __restrict__ xaggh, int N) {
    int node = blockIdx.x * 4 + (threadIdx.x >> 6);
    if (node >= N) return;
    int lane = threadIdx.x & 63;
    int half = lane >> 5, li = lane & 31;
    int begin = row_start[node], end = row_start[node + 1];
    float a0 = 0.f, a1 = 0.f, a2 = 0.f, a3 = 0.f;
    float b0 = 0.f, b1 = 0.f, b2 = 0.f, b3 = 0.f;
    for (int base = begin; base < end; base += 64) {
        int cnt = min(64, end - base);
        int myidx = (lane < cnt) ? csr_src[base + lane] : 0;
        int j = 0;
        for (; j + 3 < cnt; j += 4) {
            int s0 = __shfl(myidx, j + half);
            int s1 = __shfl(myidx, j + 2 + half);
            f16x4 v0 = *(const f16x4*)(xh + (size_t)s0 * H + li * 4);
            f16x4 v1 = *(const f16x4*)(xh + (size_t)s1 * H + li * 4);
            a0 += (float)v0[0]; a1 += (float)v0[1]; a2 += (float)v0[2]; a3 += (float)v0[3];
            b0 += (float)v1[0]; b1 += (float)v1[1]; b2 += (float)v1[2]; b3 += (float)v1[3];
        }
        for (; j < cnt; j += 2) {
            if (j + half < cnt) {
                int s0 = __shfl(myidx, j + half);
                f16x4 v0 = *(const f16x4*)(xh + (size_t)s0 * H + li * 4);
                a0 += (float)v0[0]; a1 += (float)v0[1]; a2 += (float)v0[2]; a3 += (float)v0[3];
            }
        }
    }
    a0 += b0; a1 += b1; a2 += b2; a3 += b3;
    a0 += __shfl_xor(a0, 32); a1 += __shfl_xor(a1, 32);
    a2 += __shfl_xor(a2, 32); a3 += __shfl_xor(a3, 32);
    if (half == 0) {
        f16x4 o; o[0] = (half_t)a0; o[1] = (half_t)a1; o[2] = (half_t)a2; o[3] = (half_t)a3;
        *(f16x4*)(xaggh + (size_t)node * H + li * 4) = o;
    }
}

// ---------------- fused conv+update via f16 MFMA
#define CROWS 128
#define BLDW 264   // 256 + 8 halfs pad
__global__ __launch_bounds__(256) void conv_mfma(
        const float* __restrict__ xin, const half_t* __restrict__ xh,
        const half_t* __restrict__ xaggh, const half_t* __restrict__ WtT,
        const float* __restrict__ bias,
        float* __restrict__ xout, half_t* __restrict__ xouth, int N) {
    __shared__ __align__(16) half_t sB[128 * BLDW];
    int tid = threadIdx.x;
    for (int c = tid; c < 4096; c += 256) {
        int j = c >> 5, off = (c & 31) * 8;
        *(f16x8*)&sB[j * BLDW + off] = *(const f16x8*)(WtT + j * 256 + off);
    }
    __syncthreads();

    int wave = tid >> 6, lane = tid & 63;
    int q = lane >> 4, m = lane & 15;
    int rowbase = blockIdx.x * CROWS + wave * 32;

    f32x4 acc[2][8];
#pragma unroll
    for (int rt = 0; rt < 2; ++rt)
#pragma unroll
        for (int ct = 0; ct < 8; ++ct) acc[rt][ct] = (f32x4){0.f, 0.f, 0.f, 0.f};

#pragma unroll
    for (int s = 0; s < 8; ++s) {
        const half_t* srcA = (s < 4) ? xh : xaggh;
        int koff = (s & 3) * 32 + q * 8;
        f16x8 afrag[2];
#pragma unroll
        for (int rt = 0; rt < 2; ++rt) {
            int row = rowbase + rt * 16 + m;
            row = min(row, N - 1);
            afrag[rt] = *(const f16x8*)(srcA + (size_t)row * H + koff);
        }
#pragma unroll
        for (int ct = 0; ct < 8; ++ct) {
            f16x8 bfrag = *(const f16x8*)&sB[(ct * 16 + m) * BLDW + s * 32 + q * 8];
            acc[0][ct] = __builtin_amdgcn_mfma_f32_16x16x32_f16(afrag[0], bfrag, acc[0][ct], 0, 0, 0);
            acc[1][ct] = __builtin_amdgcn_mfma_f32_16x16x32_f16(afrag[1], bfrag, acc[1][ct], 0, 0, 0);
        }
    }

#pragma unroll
    for (int rt = 0; rt < 2; ++rt) {
#pragma unroll
        for (int r = 0; r < 4; ++r) {
            int row = rowbase + rt * 16 + q * 4 + r;
            if (row < N) {
#pragma unroll
                for (int ct = 0; ct < 8; ++ct) {
                    int col = ct * 16 + m;
                    float c = acc[rt][ct][r] + bias[col];
                    float o = xin[(size_t)row * H + col] + EPS * fast_tanh(c);
                    xout[(size_t)row * H + col] = o;
                    xouth[(size_t)row * H + col] = (half_t)o;
                }
            }
        }
    }
}

// ---------------- triple pooling: 1 block/graph, 1024 thr = 8 row-slots
__global__ __launch_bounds__(1024) void pool_kernel(const float* __restrict__ x,
        const int* __restrict__ batch, float* __restrict__ pooled, int N) {
    __shared__ float ssum[8][128];
    __shared__ float smax[8][128];
    int g = blockIdx.x, t = threadIdx.x;
    int feat = t & 127, slot = t >> 7;   // 8 slots
    int lo = 0, hi = N;
    while (lo < hi) { int mid = (lo + hi) >> 1; if (batch[mid] < g) lo = mid + 1; else hi = mid; }
    int start = lo;
    hi = N;
    while (lo < hi) { int mid = (lo + hi) >> 1; if (batch[mid] < g + 1) lo = mid + 1; else hi = mid; }
    int end = lo;
    float sum = 0.f, mx = -INFINITY;
    for (int n = start + slot; n < end; n += 8) {
        float v = x[(size_t)n * H + feat];
        sum += v;
        mx = fmaxf(mx, v);
    }
    ssum[slot][feat] = sum;
    smax[slot][feat] = mx;
    __syncthreads();
    if (t < 128) {
        float s = 0.f, m = -INFINITY;
#pragma unroll
        for (int k = 0; k < 8; ++k) { s += ssum[k][t]; m = fmaxf(m, smax[k][t]); }
        int cnt = end - start;
        pooled[g * 384 + t] = s;
        pooled[g * 384 + 128 + t] = (cnt > 0) ? m : 0.f;
        pooled[g * 384 + 256 + t] = s / (float)(cnt > 0 ? cnt : 1);
    }
}

// ---------------- final 2-layer MLP with leaky relu
__global__ void mlp_kernel(const float* __restrict__ pooled, const float* __restrict__ l1_w,
                           const float* __restrict__ l1_b, const float* __restrict__ l2_w,
                           const float* __restrict__ l2_b, float* __restrict__ out) {
    __shared__ __align__(16) float sp[384];
    __shared__ __align__(16) float sh[192];
    int g = blockIdx.x, tid = threadIdx.x;  // 256 threads
    for (int i = tid; i < 384; i += 256) sp[i] = pooled[g * 384 + i];
    __syncthreads();
    if (tid < 192) {
        float acc = l1_b[tid];
        const float* wr = l1_w + (size_t)tid * 384;
        for (int k = 0; k < 384; k += 4) {
            float4 w = *(const float4*)(wr + k);
            float4 p = *(const float4*)(sp + k);
            acc += w.x * p.x + w.y * p.y + w.z * p.z + w.w * p.w;
        }
        sh[tid] = acc > 0.f ? acc : NEG * acc;
    }
    __syncthreads();
    if (tid < 64) {
        float acc = l2_b[tid];
        const float* wr = l2_w + (size_t)tid * 192;
        for (int k = 0; k < 192; k += 4) {
            float4 w = *(const float4*)(wr + k);
            float4 p = *(const float4*)(sh + k);
            acc += w.x * p.x + w.y * p.y + w.z * p.z + w.w * p.w;
        }
        out[g * 64 + tid] = acc > 0.f ? acc : NEG * acc;
    }
}

extern "C" void kernel_launch(void* const* d_in, const int* in_sizes, int n_in,
                              void* d_out, int out_size, void* d_ws, size_t ws_size,
                              hipStream_t stream) {
    const float* x0    = (const float*)d_in[0];
    const int*   edge  = (const int*)d_in[1];
    const int*   batch = (const int*)d_in[2];
    const float* W     = (const float*)d_in[3];
    const float* bias  = (const float*)d_in[4];
    const float* lin_w = (const float*)d_in[5];
    const float* l1_w  = (const float*)d_in[6];
    const float* l1_b  = (const float*)d_in[7];
    const float* l2_w  = (const float*)d_in[8];
    const float* l2_b  = (const float*)d_in[9];
    float* out = (float*)d_out;

    int N = in_sizes[0] / H;
    int E = in_sizes[1] / 2;
    const int* src = edge;
    const int* dst = edge + E;

    size_t nh = (size_t)N * H;
    float* xA      = (float*)d_ws;
    float* xB      = xA + nh;
    float* pooled  = xB + nh;
    half_t* xhA    = (half_t*)(pooled + NGRAPH * 384);
    half_t* xhB    = xhA + nh;
    half_t* xaggh  = xhB + nh;
    half_t* WtT    = xaggh + nh;              // 128*256
    int* deg       = (int*)(WtT + 128 * 256);
    int* row_start = deg + N;                 // N+1
    int* cursor    = row_start + N + 1;
    int* csr_src   = cursor + N;              // E
    int* partials  = csr_src + E;             // 64
    int* blkoff    = partials + 64;           // 64

    prep_kernel<<<128, 256, 0, stream>>>(W, lin_w, WtT);
    cast_kernel<<<((int)(nh / 4) + 255) / 256, 256, 0, stream>>>(x0, xhA, (int)(nh / 4));

    hipMemsetAsync(deg, 0, (size_t)N * sizeof(int), stream);
    count_kernel<<<(E + 255) / 256, 256, 0, stream>>>(dst, deg, E);
    int nblk = (N + SCHUNK - 1) / SCHUNK;
    scan_part<<<nblk, 256, 0, stream>>>(deg, partials, N);
    scan_mid<<<1, 64, 0, stream>>>(partials, blkoff, nblk);
    scan_final<<<nblk, 256, 0, stream>>>(deg, blkoff, row_start, cursor, N, E);
    fill_kernel<<<(E + 255) / 256, 256, 0, stream>>>(src, dst, cursor, csr_src, E);

    const float* xcur = x0;
    const half_t* xcur_h = xhA;
    for (int it = 0; it < 5; ++it) {
        gather_agg<<<(N + 3) / 4, 256, 0, stream>>>(xcur_h, row_start, csr_src, xaggh, N);
        float* xnext = (it & 1) ? xB : xA;
        half_t* xnext_h = (it & 1) ? xhA : xhB;
        conv_mfma<<<(N + CROWS - 1) / CROWS, 256, 0, stream>>>(
            xcur, xcur_h, xaggh, WtT, bias, xnext, xnext_h, N);
        xcur = xnext;
        xcur_h = xnext_h;
    }

    pool_kernel<<<NGRAPH, 1024, 0, stream>>>(xcur, batch, pooled, N);
    mlp_kernel<<<NGRAPH, 256, 0, stream>>>(pooled, l1_w, l1_b, l2_w, l2_b, out);
}